// Round 8
// baseline (134.053 us; speedup 1.0000x reference)
//
#include <hip/hip_runtime.h>

// LlamaAttention — Round 15: offline x-cvt + linear gld_lds stage.
//
// out = x @ (Wo @ Wv)^T  (softmax == I, established r0-r14).
// r14 post-mortem: 3-deep B prefetch null — VGPR=116 shows the compiler
// sank the prefetches (runtime `if(pre)` + stage temps ate the headroom).
// Phase model: stage ~8-10 (f32 reads + cvt) | K ~10 | epi ~8 vs 42
// measured. r15: (1) prep dispatch fused with cvt_x: xf = f16(x)
// PRE-SWIZZLED into the exact LDS image -> gemm stage is a linear 96 KB
// global_load_lds memcpy (no cvt, half bytes, L3-hot; rule #21: linear
// dest + inverse-swz source + swz read). (2) counted vmcnt(18) retires
// the stage DMA while 3 B-tiles stay in flight; raw s_barrier. (3) K-loop
// fully unrolled (compile-time prefetch predicate) + freed VGPRs so the
// 3-deep rotation actually holds. Bit-identical math -> absmax 0.0039.

typedef unsigned short u16;
typedef __attribute__((ext_vector_type(8))) short short8;      // 16 B
typedef __attribute__((ext_vector_type(8))) _Float16 f16x8;    // 4 VGPR MFMA frag
typedef __attribute__((ext_vector_type(4))) float float4v;

__device__ inline u16 f16b(float f) {
  union { _Float16 h; u16 u; } v; v.h = (_Float16)f; return v.u;  // v_cvt_f16_f32 RNE
}

__device__ inline u16 f32_to_bf16(float f) {        // fallback path only
  union { float f; unsigned int u; } v; v.f = f;
  unsigned int r = v.u + 0x7FFF + ((v.u >> 16) & 1);
  return (u16)(r >> 16);
}

__device__ inline void gld_lds16(const u16* g, u16* l) {
  auto gp = (const __attribute__((address_space(1))) unsigned int*)(g);
  auto lp = (__attribute__((address_space(3))) unsigned int*)(l);
  __builtin_amdgcn_global_load_lds(gp, lp, 16, 0, 0);
}

// ---------------- prep (fused): W = Wo @ Wv  +  xf = swizzled f16(x) -----
// wt layout: element (o, h) at wt[(h>>5)*24576 + o*32 + ((h>>3)&3)*8 + (h&7)]
// (wave frag load = 1 KB contiguous). Bit-identical W vs r10-r14.
// xf layout: xf[R*768 + cs*8 + e] = f16(x[R*768 + (cs^(R&7))*8 + e])
// == the exact LDS image gemm wants, so staging is a linear copy.
// Grid 2624 = 576 prep blocks + 2048 cvt blocks (8 rows each).
// (Launching with grid 576 gives prep-only behavior for the legacy tier.)
__global__ __launch_bounds__(256)
void prep_fused(const float* __restrict__ Wv, const float* __restrict__ Wo,
                const float* __restrict__ x,
                u16* __restrict__ wt, u16* __restrict__ xf) {
  __shared__ __align__(16) float wo[4][256];            // 4 KB (prep branch)
  if (blockIdx.x < 576) {
    const int og = blockIdx.x / 3, hc = blockIdx.x % 3; // 192 o-grp x 3 h-chunk
    const int o0 = og * 4;
    ((float4v*)&wo[0][0])[threadIdx.x] =
        ((const float4v*)(Wo + (size_t)o0 * 256))[threadIdx.x];
    __syncthreads();
    const int h = hc * 256 + threadIdx.x;
    float acc[4] = {0.f, 0.f, 0.f, 0.f};
    float wvA[8], wvB[8];
#pragma unroll
    for (int u = 0; u < 8; ++u) wvA[u] = Wv[(size_t)u * 768 + h];

#define PFMA(wv_, kk_)                                                       \
    _Pragma("unroll")                                                        \
    for (int j = 0; j < 4; ++j) {                                            \
      float4v c0 = *(const float4v*)(&wo[j][kk_]);                           \
      float4v c1 = *(const float4v*)(&wo[j][(kk_) + 4]);                     \
      acc[j] = fmaf(c0[0], wv_[0], acc[j]);                                  \
      acc[j] = fmaf(c0[1], wv_[1], acc[j]);                                  \
      acc[j] = fmaf(c0[2], wv_[2], acc[j]);                                  \
      acc[j] = fmaf(c0[3], wv_[3], acc[j]);                                  \
      acc[j] = fmaf(c1[0], wv_[4], acc[j]);                                  \
      acc[j] = fmaf(c1[1], wv_[5], acc[j]);                                  \
      acc[j] = fmaf(c1[2], wv_[6], acc[j]);                                  \
      acc[j] = fmaf(c1[3], wv_[7], acc[j]);                                  \
    }

    for (int k = 0; k < 240; k += 16) {
#pragma unroll
      for (int u = 0; u < 8; ++u) wvB[u] = Wv[(size_t)(k + 8 + u) * 768 + h];
      PFMA(wvA, k)
#pragma unroll
      for (int u = 0; u < 8; ++u) wvA[u] = Wv[(size_t)(k + 16 + u) * 768 + h];
      PFMA(wvB, k + 8)
    }
#pragma unroll
    for (int u = 0; u < 8; ++u) wvB[u] = Wv[(size_t)(248 + u) * 768 + h];
    PFMA(wvA, 240)
    PFMA(wvB, 248)
#undef PFMA

    const int kt = h >> 5, qq = (h >> 3) & 3, e = h & 7;
#pragma unroll
    for (int j = 0; j < 4; ++j)
      wt[(size_t)kt * 24576 + (o0 + j) * 32 + qq * 8 + e] = f16b(acc[j]);
  } else {
    // ---- cvt_x: 8 rows x 96 chunks per block, 3 chunks/thread ----
    const int R0 = (blockIdx.x - 576) * 8;
#pragma unroll
    for (int j = 0; j < 3; ++j) {
      const int idx = j * 256 + threadIdx.x;        // 0..767
      const int rl = idx / 96, cs = idx - rl * 96;  // const-div -> mul/shift
      const int R = R0 + rl;
      const float* src = x + (size_t)R * 768 + ((cs ^ (R & 7)) << 3);
      float4v v0 = *(const float4v*)(src);
      float4v v1 = *(const float4v*)(src + 4);
      union { u16 h[8]; short8 s; } p;
#pragma unroll
      for (int e = 0; e < 4; ++e) { p.h[e] = f16b(v0[e]); p.h[e + 4] = f16b(v1[e]); }
      *(short8*)(xf + (size_t)R * 768 + (cs << 3)) = p.s;
    }
  }
}

// ---------------- main: out[16384,768] = x @ W^T, zero-barrier loop -------
// Block: 512 thr / 8 waves; 64 rows x 768 cols; wave w owns cols w*96..+95
// (disjoint -> W read once per block). Stage = linear gld_lds memcpy of
// the pre-swizzled xf stripe (96 KB); A-frag reads use chunk^(row&7).
__global__ __launch_bounds__(512, 2)
void gemm_xw(const u16* __restrict__ xf, const u16* __restrict__ wt,
             float* __restrict__ out) {
  __shared__ __align__(16) u16 S[64 * 768];       // 96 KB -> 1 block/CU

  const int tid = threadIdx.x;
  const int w = tid >> 6, l = tid & 63;
  const int q = l >> 4, mr = l & 15;
  const int row0 = blockIdx.x * 64;

  // B-frag lane base: wt + col*32 + q*8, col = w*96 + jn*16 + mr
  const u16* wl = wt + (w * 96 + mr) * 32 + q * 8;
  const int akey = mr & 7;

  f16x8 a0[4], a1[4], a2[4], b0[6], b1[6], b2[6];

#define LDA(av_, kt_)                                                        \
  _Pragma("unroll")                                                          \
  for (int im = 0; im < 4; ++im)                                             \
    av_[im] = *(const f16x8*)(                                               \
        &S[(im * 16 + mr) * 768 + ((((kt_) * 4 + q) ^ akey) << 3)]);

#define LDB(bv_, kt_)                                                        \
  { const u16* gp = wl + (size_t)(kt_) * 24576;                              \
    _Pragma("unroll")                                                        \
    for (int jn = 0; jn < 6; ++jn)                                           \
      bv_[jn] = *(const f16x8*)(gp + jn * 512); }

  // ---- stage: 12 linear gld_lds (oldest in FIFO), then 3 B-tiles ----
  {
    const u16* xsrc = xf + (size_t)blockIdx.x * 49152 + tid * 8;
#pragma unroll
    for (int j = 0; j < 12; ++j)
      gld_lds16(xsrc + j * 4096, &S[j * 4096 + tid * 8]);
  }
  asm volatile("" ::: "memory");                 // pin: gld_lds before B loads
  LDB(b0, 0)
  LDB(b1, 1)
  LDB(b2, 2)
  asm volatile("s_waitcnt vmcnt(18)" ::: "memory");  // 12 gld_lds retired;
  __builtin_amdgcn_s_barrier();                      // 18 B loads in flight

  float4v acc[4][6];
#pragma unroll
  for (int i = 0; i < 4; ++i)
#pragma unroll
    for (int j = 0; j < 6; ++j) acc[i][j] = (float4v){0.f, 0.f, 0.f, 0.f};

#define MM(av_, bv_)                                                         \
  { __builtin_amdgcn_s_setprio(1);                                           \
    _Pragma("unroll")                                                        \
    for (int im = 0; im < 4; ++im)                                           \
      _Pragma("unroll")                                                      \
      for (int jn = 0; jn < 6; ++jn)                                         \
        acc[im][jn] = __builtin_amdgcn_mfma_f32_16x16x32_f16(                \
            av_[im], bv_[jn], acc[im][jn], 0, 0, 0);                         \
    __builtin_amdgcn_s_setprio(0); }

  LDA(a0, 0)
  LDA(a1, 1)
  LDA(a2, 2)

  // Fully unrolled: prefetch predicate is compile-time, 3-deep rotation.
#pragma unroll
  for (int t = 0; t < 24; t += 3) {
    MM(a0, b0)
    if (t < 21) { LDB(b0, t + 3) LDA(a0, t + 3) }
    MM(a1, b1)
    if (t < 21) { LDB(b1, t + 4) LDA(a1, t + 4) }
    MM(a2, b2)
    if (t < 21) { LDB(b2, t + 5) LDA(a2, t + 5) }
  }

#undef LDA
#undef LDB
#undef MM

  // ---- epilogue: C/D col=lane&15, row=q*4+reg (m89-verified) ----
#pragma unroll
  for (int im = 0; im < 4; ++im)
#pragma unroll
    for (int jn = 0; jn < 6; ++jn) {
      const int r0 = row0 + im * 16 + q * 4;
      const int c  = w * 96 + jn * 16 + mr;
#pragma unroll
      for (int r = 0; r < 4; ++r)
        out[(size_t)(r0 + r) * 768 + c] = acc[im][jn][r];
    }
}

// ---------------- legacy tier (ws fits wt only): r14 gemm, verified -------
__global__ __launch_bounds__(512, 2)
void gemm_legacy(const float* __restrict__ x, const u16* __restrict__ wt,
                 float* __restrict__ out) {
  __shared__ __align__(16) u16 S[64 * 768];       // 96 KB -> 1 block/CU

  const int tid = threadIdx.x;
  const int w = tid >> 6, l = tid & 63;
  const int q = l >> 4, mr = l & 15;
  const int row0 = blockIdx.x * 64;

  const u16* wl = wt + (w * 96 + mr) * 32 + q * 8;
  const int akey = mr & 7;

  f16x8 a0[4], a1[4], a2[4], b0[6], b1[6], b2[6];

#define LDA(av_, kt_)                                                        \
  _Pragma("unroll")                                                          \
  for (int im = 0; im < 4; ++im)                                             \
    av_[im] = *(const f16x8*)(                                               \
        &S[(im * 16 + mr) * 768 + ((((kt_) * 4 + q) ^ akey) << 3)]);

#define LDB(bv_, kt_)                                                        \
  { const u16* gp = wl + (size_t)(kt_) * 24576;                              \
    _Pragma("unroll")                                                        \
    for (int jn = 0; jn < 6; ++jn)                                           \
      bv_[jn] = *(const f16x8*)(gp + jn * 512); }

  LDB(b0, 0)
  LDB(b1, 1)
  LDB(b2, 2)

  {
    const int sr = ((w & 3) << 4) + mr;
    const int half = w >> 2;
    const float* gr = x + (size_t)(row0 + sr) * 768;
    u16* lr = S + sr * 768;
    const int key = sr & 7;
#pragma unroll
    for (int j = 0; j < 12; ++j) {
      const int c = q + 4 * (2 * j + half);
      float4v v0 = *(const float4v*)(gr + c * 8);
      float4v v1 = *(const float4v*)(gr + c * 8 + 4);
      union { u16 h[8]; short8 s; } p;
#pragma unroll
      for (int e = 0; e < 4; ++e) { p.h[e] = f16b(v0[e]); p.h[e + 4] = f16b(v1[e]); }
      *(short8*)(lr + ((c ^ key) << 3)) = p.s;
    }
  }
  __syncthreads();

  float4v acc[4][6];
#pragma unroll
  for (int i = 0; i < 4; ++i)
#pragma unroll
    for (int j = 0; j < 6; ++j) acc[i][j] = (float4v){0.f, 0.f, 0.f, 0.f};

#define MM(av_, bv_)                                                         \
  { __builtin_amdgcn_s_setprio(1);                                           \
    _Pragma("unroll")                                                        \
    for (int im = 0; im < 4; ++im)                                           \
      _Pragma("unroll")                                                      \
      for (int jn = 0; jn < 6; ++jn)                                         \
        acc[im][jn] = __builtin_amdgcn_mfma_f32_16x16x32_f16(                \
            av_[im], bv_[jn], acc[im][jn], 0, 0, 0);                         \
    __builtin_amdgcn_s_setprio(0); }

  LDA(a0, 0)
  LDA(a1, 1)
  LDA(a2, 2)

#pragma unroll
  for (int t = 0; t < 24; t += 3) {
    MM(a0, b0)
    if (t < 21) { LDB(b0, t + 3) LDA(a0, t + 3) }
    MM(a1, b1)
    if (t < 21) { LDB(b1, t + 4) LDA(a1, t + 4) }
    MM(a2, b2)
    if (t < 21) { LDB(b2, t + 5) LDA(a2, t + 5) }
  }

#undef LDA
#undef LDB
#undef MM

#pragma unroll
  for (int im = 0; im < 4; ++im)
#pragma unroll
    for (int jn = 0; jn < 6; ++jn) {
      const int r0 = row0 + im * 16 + q * 4;
      const int c  = w * 96 + jn * 16 + mr;
#pragma unroll
      for (int r = 0; r < 4; ++r)
        out[(size_t)(r0 + r) * 768 + c] = acc[im][jn][r];
    }
}

// ---------------- fallback (no workspace): verified r7 kernel ----------------
__global__ __launch_bounds__(512, 1)
void fused_fallback(const float* __restrict__ x,
                    const float* __restrict__ Wv, const float* __restrict__ Wo,
                    float* __restrict__ out) {
  __shared__ __align__(16) u16 As[64 * 32];
  __shared__ __align__(16) u16 Bs[256 * 32];
  __shared__ __align__(16) u16 Vs[64 * 264];

  const int tid = threadIdx.x;
  const int w  = tid >> 6, l = tid & 63;
  const int q  = l >> 4, mr = l & 15;
  const int wm = w & 1, wn = w >> 1;
  const int row0 = blockIdx.x * 64;
  const int xr = tid >> 3, xg = (tid & 7) * 4;
  const int wr = tid >> 1, wh = (tid & 1) * 16;

  float4v acc[2][4];
#pragma unroll
  for (int i = 0; i < 2; ++i)
#pragma unroll
    for (int j = 0; j < 4; ++j) acc[i][j] = (float4v){0.f, 0.f, 0.f, 0.f};

  for (int kt = 0; kt < 24; ++kt) {
    const int k0 = kt * 32;
    {
      float4v v = *(const float4v*)(x + (size_t)(row0 + xr) * 768 + k0 + xg);
      union { u16 h[4]; uint2 u; } p;
      p.h[0] = f32_to_bf16(v[0]); p.h[1] = f32_to_bf16(v[1]);
      p.h[2] = f32_to_bf16(v[2]); p.h[3] = f32_to_bf16(v[3]);
      *(uint2*)(As + xr * 32 + xg) = p.u;
    }
    {
      const float* g = Wv + (size_t)wr * 768 + k0 + wh;
      union { u16 h[16]; short8 s[2]; } p;
#pragma unroll
      for (int u = 0; u < 4; ++u) {
        float4v v = *(const float4v*)(g + u * 4);
        p.h[u * 4 + 0] = f32_to_bf16(v[0]); p.h[u * 4 + 1] = f32_to_bf16(v[1]);
        p.h[u * 4 + 2] = f32_to_bf16(v[2]); p.h[u * 4 + 3] = f32_to_bf16(v[3]);
      }
      *(short8*)(Bs + wr * 32 + wh) = p.s[0];
      *(short8*)(Bs + wr * 32 + wh + 8) = p.s[1];
    }
    __syncthreads();

    short8 a[2], b[4];
#pragma unroll
    for (int i = 0; i < 2; ++i)
      a[i] = *(const short8*)(As + (wm * 32 + i * 16 + mr) * 32 + q * 8);
#pragma unroll
    for (int j = 0; j < 4; ++j)
      b[j] = *(const short8*)(Bs + (wn * 64 + j * 16 + mr) * 32 + q * 8);
#pragma unroll
    for (int i = 0; i < 2; ++i)
#pragma unroll
      for (int j = 0; j < 4; ++j)
        acc[i][j] = __builtin_amdgcn_mfma_f32_16x16x32_bf16(a[i], b[j], acc[i][j], 0, 0, 0);
    __syncthreads();
  }

#pragma unroll
  for (int i = 0; i < 2; ++i)
#pragma unroll
    for (int j = 0; j < 4; ++j) {
      int row = wm * 32 + i * 16 + q * 4;
      int col = wn * 64 + j * 16 + mr;
#pragma unroll
      for (int r = 0; r < 4; ++r)
        Vs[(row + r) * 264 + col] = f32_to_bf16(acc[i][j][r]);
    }
  __syncthreads();

  for (int c = 0; c < 3; ++c) {
    float4v acc2[2][4];
#pragma unroll
    for (int i = 0; i < 2; ++i)
#pragma unroll
      for (int j = 0; j < 4; ++j) acc2[i][j] = (float4v){0.f, 0.f, 0.f, 0.f};

    for (int kt = 0; kt < 8; ++kt) {
      const int k0 = kt * 32;
      {
        const float* g = Wo + (size_t)(c * 256 + wr) * 256 + k0 + wh;
        union { u16 h[16]; short8 s[2]; } p;
#pragma unroll
        for (int u = 0; u < 4; ++u) {
          float4v v = *(const float4v*)(g + u * 4);
          p.h[u * 4 + 0] = f32_to_bf16(v[0]); p.h[u * 4 + 1] = f32_to_bf16(v[1]);
          p.h[u * 4 + 2] = f32_to_bf16(v[2]); p.h[u * 4 + 3] = f32_to_bf16(v[3]);
        }
        *(short8*)(Bs + wr * 32 + wh) = p.s[0];
        *(short8*)(Bs + wr * 32 + wh + 8) = p.s[1];
      }
      __syncthreads();

      short8 a[2], b[4];
#pragma unroll
      for (int i = 0; i < 2; ++i)
        a[i] = *(const short8*)(Vs + (wm * 32 + i * 16 + mr) * 264 + k0 + q * 8);
#pragma unroll
      for (int j = 0; j < 4; ++j)
        b[j] = *(const short8*)(Bs + (wn * 64 + j * 16 + mr) * 32 + q * 8);
#pragma unroll
      for (int i = 0; i < 2; ++i)
#pragma unroll
        for (int j = 0; j < 4; ++j)
          acc2[i][j] = __builtin_amdgcn_mfma_f32_16x16x32_bf16(a[i], b[j], acc2[i][j], 0, 0, 0);
      __syncthreads();
    }

#pragma unroll
    for (int i = 0; i < 2; ++i)
#pragma unroll
      for (int j = 0; j < 4; ++j) {
        int row = row0 + wm * 32 + i * 16 + q * 4;
        int col = c * 256 + wn * 64 + j * 16 + mr;
#pragma unroll
        for (int r = 0; r < 4; ++r)
          out[(size_t)(row + r) * 768 + col] = acc2[i][j][r];
      }
  }
}

extern "C" void kernel_launch(void* const* d_in, const int* in_sizes, int n_in,
                              void* d_out, int out_size, void* d_ws, size_t ws_size,
                              hipStream_t stream) {
  (void)in_sizes; (void)n_in; (void)out_size;
  const float* x  = (const float*)d_in[0];  // [16384, 768]
  const float* Wv = (const float*)d_in[3];  // [256, 768]
  const float* Wo = (const float*)d_in[4];  // [768, 256]
  float* out = (float*)d_out;

  const size_t WT_BYTES = (size_t)768 * 768 * 2;            // 1.18 MB
  const size_t XF_BYTES = (size_t)16384 * 768 * 2;          // 25.2 MB

  if (ws_size >= WT_BYTES + XF_BYTES) {
    u16* wt = (u16*)d_ws;
    u16* xf = wt + 768 * 768;
    prep_fused<<<dim3(2624), dim3(256), 0, stream>>>(Wv, Wo, x, wt, xf);
    gemm_xw<<<dim3(256), dim3(512), 0, stream>>>(xf, wt, out);
  } else if (ws_size >= WT_BYTES) {
    u16* wt = (u16*)d_ws;
    prep_fused<<<dim3(576), dim3(256), 0, stream>>>(Wv, Wo, x, wt, nullptr);
    gemm_legacy<<<dim3(256), dim3(512), 0, stream>>>(x, wt, out);
  } else {
    fused_fallback<<<dim3(256), dim3(512), 0, stream>>>(x, Wv, Wo, out);
  }
}

// Round 9
// 132.580 us; speedup vs baseline: 1.0111x; 1.0111x over previous
//
#include <hip/hip_runtime.h>

// LlamaAttention — Round 16: r12 structure + asm-pinned 2-deep B pipeline.
//
// out = x @ (Wo @ Wv)^T  (softmax == I, established r0-r15).
// r15 post-mortem: offline cvt_x = wash (prep +12us, gemm -12us, 2x x reads).
// r14 post-mortem: compiler ignored the 3-deep C++ prefetch (VGPR=116).
// r16: inline-asm global_load_dwordx4 B-stream + hand-counted
// s_waitcnt vmcnt(12/6/0) + sched_barrier(0) fences (rule #18). Two
// B-tiles always in flight (~500 cyc prefetch distance >= L2 latency).
// Raw lgkmcnt(0)+s_barrier after stage keeps the prologue's 18 B loads
// in flight (no vmcnt(0) drain). Everything else identical to r12's
// measured-42.4us kernel: inline-cvt stage, 64-row stripes, 256 blocks
// = 1/CU, W read once per block, zero further barriers.

typedef unsigned short u16;
typedef __attribute__((ext_vector_type(8))) short short8;      // 16 B
typedef __attribute__((ext_vector_type(8))) _Float16 f16x8;    // 4 VGPR MFMA frag
typedef __attribute__((ext_vector_type(4))) float float4v;

__device__ inline u16 f16b(float f) {
  union { _Float16 h; u16 u; } v; v.h = (_Float16)f; return v.u;  // v_cvt_f16_f32 RNE
}

__device__ inline u16 f32_to_bf16(float f) {        // fallback path only
  union { float f; unsigned int u; } v; v.f = f;
  unsigned int r = v.u + 0x7FFF + ((v.u >> 16) & 1);
  return (u16)(r >> 16);
}

// ---------------- prep: W = Wo @ Wv, fp32 accum, f16 tiled ----------------
// wt layout: element (o, h) at wt[(h>>5)*24576 + o*32 + ((h>>3)&3)*8 + (h&7)]
// (wave frag load = 1 KB contiguous). Bit-identical W vs r10-r15.
__global__ __launch_bounds__(256)
void prep_w(const float* __restrict__ Wv, const float* __restrict__ Wo,
            u16* __restrict__ wt) {
  __shared__ __align__(16) float wo[4][256];            // 4 KB
  const int og = blockIdx.x / 3, hc = blockIdx.x % 3;   // 192 o-grp x 3 h-chunk
  const int o0 = og * 4;
  ((float4v*)&wo[0][0])[threadIdx.x] =
      ((const float4v*)(Wo + (size_t)o0 * 256))[threadIdx.x];
  __syncthreads();
  const int h = hc * 256 + threadIdx.x;
  float acc[4] = {0.f, 0.f, 0.f, 0.f};
  float wvA[8], wvB[8];
#pragma unroll
  for (int u = 0; u < 8; ++u) wvA[u] = Wv[(size_t)u * 768 + h];

#define PFMA(wv_, kk_)                                                       \
  _Pragma("unroll")                                                          \
  for (int j = 0; j < 4; ++j) {                                              \
    float4v c0 = *(const float4v*)(&wo[j][kk_]);                             \
    float4v c1 = *(const float4v*)(&wo[j][(kk_) + 4]);                       \
    acc[j] = fmaf(c0[0], wv_[0], acc[j]);                                    \
    acc[j] = fmaf(c0[1], wv_[1], acc[j]);                                    \
    acc[j] = fmaf(c0[2], wv_[2], acc[j]);                                    \
    acc[j] = fmaf(c0[3], wv_[3], acc[j]);                                    \
    acc[j] = fmaf(c1[0], wv_[4], acc[j]);                                    \
    acc[j] = fmaf(c1[1], wv_[5], acc[j]);                                    \
    acc[j] = fmaf(c1[2], wv_[6], acc[j]);                                    \
    acc[j] = fmaf(c1[3], wv_[7], acc[j]);                                    \
  }

  for (int k = 0; k < 240; k += 16) {
#pragma unroll
    for (int u = 0; u < 8; ++u) wvB[u] = Wv[(size_t)(k + 8 + u) * 768 + h];
    PFMA(wvA, k)
#pragma unroll
    for (int u = 0; u < 8; ++u) wvA[u] = Wv[(size_t)(k + 16 + u) * 768 + h];
    PFMA(wvB, k + 8)
  }
#pragma unroll
  for (int u = 0; u < 8; ++u) wvB[u] = Wv[(size_t)(248 + u) * 768 + h];
  PFMA(wvA, 240)
  PFMA(wvB, 248)
#undef PFMA

  const int kt = h >> 5, qq = (h >> 3) & 3, e = h & 7;
#pragma unroll
  for (int j = 0; j < 4; ++j)
    wt[(size_t)kt * 24576 + (o0 + j) * 32 + qq * 8 + e] = f16b(acc[j]);
}

// ---------------- main: out[16384,768] = x @ W^T, asm-pinned pipeline -----
// Block: 512 thr / 8 waves; 64 rows x 768 cols; wave w owns cols w*96..+95
// (disjoint -> W read once per block). LDS: x stripe f16 [64][96 chunks],
// chunk stored at c^(row&7) (A-frag reads 2-way max = free).
__global__ __launch_bounds__(512, 2)
void gemm_xw(const float* __restrict__ x, const u16* __restrict__ wt,
             float* __restrict__ out) {
  __shared__ __align__(16) u16 S[64 * 768];       // 96 KB -> 1 block/CU

  const int tid = threadIdx.x;
  const int w = tid >> 6, l = tid & 63;
  const int q = l >> 4, mr = l & 15;
  const int row0 = blockIdx.x * 64;

  // B-frag lane base: wt + col*32 + q*8, col = w*96 + jn*16 + mr
  const u16* wl = wt + (w * 96 + mr) * 32 + q * 8;
  const int akey = mr & 7;

  f16x8 a0[4], a1[4], a2[4], b0[6], b1[6], b2[6];

// One 16B global load, asm-pinned (compiler cannot sink/serialize it).
#define GLD_OFF(dst_, base_, OFFSTR)                                         \
  asm volatile("global_load_dwordx4 %0, %1, off offset:" OFFSTR              \
               : "=v"(dst_) : "v"(base_) : "memory");

// jn stride = 512 u16 = 1024 B; offsets must stay < 4096 -> two bases.
#define LDB_ASM(bv_, kt_)                                                    \
  { const u16* gbase  = wl + (size_t)(kt_) * 24576;                          \
    const u16* gbase2 = gbase + 2048;                                        \
    GLD_OFF(bv_[0], gbase,  "0")                                             \
    GLD_OFF(bv_[1], gbase,  "1024")                                          \
    GLD_OFF(bv_[2], gbase,  "2048")                                          \
    GLD_OFF(bv_[3], gbase,  "3072")                                          \
    GLD_OFF(bv_[4], gbase2, "0")                                             \
    GLD_OFF(bv_[5], gbase2, "1024") }

#define LDA(av_, kt_)                                                        \
  _Pragma("unroll")                                                          \
  for (int im = 0; im < 4; ++im)                                             \
    av_[im] = *(const f16x8*)(                                               \
        &S[(im * 16 + mr) * 768 + ((((kt_) * 4 + q) ^ akey) << 3)]);

// Counted wait + scheduling fence (rule #18: MFMA hoists past asm waitcnt
// without sched_barrier).
#define WAITB(NSTR)                                                          \
  asm volatile("s_waitcnt vmcnt(" NSTR ")" ::: "memory");                    \
  __builtin_amdgcn_sched_barrier(0);

#define MM(av_, bv_)                                                         \
  { __builtin_amdgcn_s_setprio(1);                                           \
    _Pragma("unroll")                                                        \
    for (int im = 0; im < 4; ++im)                                           \
      _Pragma("unroll")                                                      \
      for (int jn = 0; jn < 6; ++jn)                                         \
        acc[im][jn] = __builtin_amdgcn_mfma_f32_16x16x32_f16(                \
            av_[im], bv_[jn], acc[im][jn], 0, 0, 0);                         \
    __builtin_amdgcn_s_setprio(0); }

  // ---- prologue: 18 asm B loads in flight, then stage under them ----
  LDB_ASM(b0, 0)
  LDB_ASM(b1, 1)
  LDB_ASM(b2, 2)

  // stage x[64][768] fp32 -> LDS f16, chunk-swizzled (r12-measured code)
  {
    const int sr = ((w & 3) << 4) + mr;           // row 0..63
    const int half = w >> 2;                      // even/odd chunk quads
    const float* gr = x + (size_t)(row0 + sr) * 768;
    u16* lr = S + sr * 768;
    const int key = sr & 7;
#pragma unroll
    for (int j = 0; j < 12; ++j) {
      const int c = q + 4 * (2 * j + half);       // chunk 0..95
      float4v v0 = *(const float4v*)(gr + c * 8);
      float4v v1 = *(const float4v*)(gr + c * 8 + 4);
      union { u16 h[8]; short8 s; } p;
#pragma unroll
      for (int e = 0; e < 4; ++e) { p.h[e] = f16b(v0[e]); p.h[e + 4] = f16b(v1[e]); }
      *(short8*)(lr + ((c ^ key) << 3)) = p.s;
    }
  }
  // Raw barrier: drain only LDS writes; B loads STAY in flight.
  asm volatile("s_waitcnt lgkmcnt(0)" ::: "memory");
  __builtin_amdgcn_s_barrier();

  float4v acc[4][6];
#pragma unroll
  for (int i = 0; i < 4; ++i)
#pragma unroll
    for (int j = 0; j < 6; ++j) acc[i][j] = (float4v){0.f, 0.f, 0.f, 0.f};

  LDA(a0, 0)
  LDA(a1, 1)
  LDA(a2, 2)

  // ---- steady: uniform body, 2 B-tiles always in flight ----
  // Invariant at each WAITB(12): 18 B loads outstanding; retires oldest 6.
  // b-issue after MM is pinned by WAR on the b regs; a-ds_read likewise.
  for (int t = 0; t < 21; t += 3) {
    WAITB("12") MM(a0, b0) LDB_ASM(b0, t + 3) LDA(a0, t + 3)
    WAITB("12") MM(a1, b1) LDB_ASM(b1, t + 4) LDA(a1, t + 4)
    WAITB("12") MM(a2, b2) LDB_ASM(b2, t + 5) LDA(a2, t + 5)
  }
  // tail: tiles 21, 22, 23 already issued (and a-sets loaded) at t=18
  WAITB("12") MM(a0, b0)
  WAITB("6")  MM(a1, b1)
  WAITB("0")  MM(a2, b2)

#undef GLD_OFF
#undef LDB_ASM
#undef LDA
#undef WAITB
#undef MM

  // ---- epilogue: C/D col=lane&15, row=q*4+reg (m89-verified) ----
#pragma unroll
  for (int im = 0; im < 4; ++im)
#pragma unroll
    for (int jn = 0; jn < 6; ++jn) {
      const int r0 = row0 + im * 16 + q * 4;
      const int c  = w * 96 + jn * 16 + mr;
#pragma unroll
      for (int r = 0; r < 4; ++r)
        out[(size_t)(r0 + r) * 768 + c] = acc[im][jn][r];
    }
}

// ---------------- fallback (no workspace): verified r7 kernel ----------------
__global__ __launch_bounds__(512, 1)
void fused_fallback(const float* __restrict__ x,
                    const float* __restrict__ Wv, const float* __restrict__ Wo,
                    float* __restrict__ out) {
  __shared__ __align__(16) u16 As[64 * 32];
  __shared__ __align__(16) u16 Bs[256 * 32];
  __shared__ __align__(16) u16 Vs[64 * 264];

  const int tid = threadIdx.x;
  const int w  = tid >> 6, l = tid & 63;
  const int q  = l >> 4, mr = l & 15;
  const int wm = w & 1, wn = w >> 1;
  const int row0 = blockIdx.x * 64;
  const int xr = tid >> 3, xg = (tid & 7) * 4;
  const int wr = tid >> 1, wh = (tid & 1) * 16;

  float4v acc[2][4];
#pragma unroll
  for (int i = 0; i < 2; ++i)
#pragma unroll
    for (int j = 0; j < 4; ++j) acc[i][j] = (float4v){0.f, 0.f, 0.f, 0.f};

  for (int kt = 0; kt < 24; ++kt) {
    const int k0 = kt * 32;
    {
      float4v v = *(const float4v*)(x + (size_t)(row0 + xr) * 768 + k0 + xg);
      union { u16 h[4]; uint2 u; } p;
      p.h[0] = f32_to_bf16(v[0]); p.h[1] = f32_to_bf16(v[1]);
      p.h[2] = f32_to_bf16(v[2]); p.h[3] = f32_to_bf16(v[3]);
      *(uint2*)(As + xr * 32 + xg) = p.u;
    }
    {
      const float* g = Wv + (size_t)wr * 768 + k0 + wh;
      union { u16 h[16]; short8 s[2]; } p;
#pragma unroll
      for (int u = 0; u < 4; ++u) {
        float4v v = *(const float4v*)(g + u * 4);
        p.h[u * 4 + 0] = f32_to_bf16(v[0]); p.h[u * 4 + 1] = f32_to_bf16(v[1]);
        p.h[u * 4 + 2] = f32_to_bf16(v[2]); p.h[u * 4 + 3] = f32_to_bf16(v[3]);
      }
      *(short8*)(Bs + wr * 32 + wh) = p.s[0];
      *(short8*)(Bs + wr * 32 + wh + 8) = p.s[1];
    }
    __syncthreads();

    short8 a[2], b[4];
#pragma unroll
    for (int i = 0; i < 2; ++i)
      a[i] = *(const short8*)(As + (wm * 32 + i * 16 + mr) * 32 + q * 8);
#pragma unroll
    for (int j = 0; j < 4; ++j)
      b[j] = *(const short8*)(Bs + (wn * 64 + j * 16 + mr) * 32 + q * 8);
#pragma unroll
    for (int i = 0; i < 2; ++i)
#pragma unroll
      for (int j = 0; j < 4; ++j)
        acc[i][j] = __builtin_amdgcn_mfma_f32_16x16x32_bf16(a[i], b[j], acc[i][j], 0, 0, 0);
    __syncthreads();
  }

#pragma unroll
  for (int i = 0; i < 2; ++i)
#pragma unroll
    for (int j = 0; j < 4; ++j) {
      int row = wm * 32 + i * 16 + q * 4;
      int col = wn * 64 + j * 16 + mr;
#pragma unroll
      for (int r = 0; r < 4; ++r)
        Vs[(row + r) * 264 + col] = f32_to_bf16(acc[i][j][r]);
    }
  __syncthreads();

  for (int c = 0; c < 3; ++c) {
    float4v acc2[2][4];
#pragma unroll
    for (int i = 0; i < 2; ++i)
#pragma unroll
      for (int j = 0; j < 4; ++j) acc2[i][j] = (float4v){0.f, 0.f, 0.f, 0.f};

    for (int kt = 0; kt < 8; ++kt) {
      const int k0 = kt * 32;
      {
        const float* g = Wo + (size_t)(c * 256 + wr) * 256 + k0 + wh;
        union { u16 h[16]; short8 s[2]; } p;
#pragma unroll
        for (int u = 0; u < 4; ++u) {
          float4v v = *(const float4v*)(g + u * 4);
          p.h[u * 4 + 0] = f32_to_bf16(v[0]); p.h[u * 4 + 1] = f32_to_bf16(v[1]);
          p.h[u * 4 + 2] = f32_to_bf16(v[2]); p.h[u * 4 + 3] = f32_to_bf16(v[3]);
        }
        *(short8*)(Bs + wr * 32 + wh) = p.s[0];
        *(short8*)(Bs + wr * 32 + wh + 8) = p.s[1];
      }
      __syncthreads();

      short8 a[2], b[4];
#pragma unroll
      for (int i = 0; i < 2; ++i)
        a[i] = *(const short8*)(Vs + (wm * 32 + i * 16 + mr) * 264 + k0 + q * 8);
#pragma unroll
      for (int j = 0; j < 4; ++j)
        b[j] = *(const short8*)(Bs + (wn * 64 + j * 16 + mr) * 32 + q * 8);
#pragma unroll
      for (int i = 0; i < 2; ++i)
#pragma unroll
        for (int j = 0; j < 4; ++j)
          acc2[i][j] = __builtin_amdgcn_mfma_f32_16x16x32_bf16(a[i], b[j], acc2[i][j], 0, 0, 0);
      __syncthreads();
    }

#pragma unroll
    for (int i = 0; i < 2; ++i)
#pragma unroll
      for (int j = 0; j < 4; ++j) {
        int row = row0 + wm * 32 + i * 16 + q * 4;
        int col = c * 256 + wn * 64 + j * 16 + mr;
#pragma unroll
        for (int r = 0; r < 4; ++r)
          out[(size_t)(row + r) * 768 + col] = acc2[i][j][r];
      }
  }
}

extern "C" void kernel_launch(void* const* d_in, const int* in_sizes, int n_in,
                              void* d_out, int out_size, void* d_ws, size_t ws_size,
                              hipStream_t stream) {
  (void)in_sizes; (void)n_in; (void)out_size;
  const float* x  = (const float*)d_in[0];  // [16384, 768]
  const float* Wv = (const float*)d_in[3];  // [256, 768]
  const float* Wo = (const float*)d_in[4];  // [768, 256]
  float* out = (float*)d_out;

  if (ws_size >= (size_t)768 * 768 * 2) {   // 1.18 MB f16 combined weight
    u16* wt = (u16*)d_ws;
    prep_w<<<dim3(576), dim3(256), 0, stream>>>(Wv, Wo, wt);
    gemm_xw<<<dim3(256), dim3(512), 0, stream>>>(x, wt, out);
  } else {
    fused_fallback<<<dim3(256), dim3(512), 0, stream>>>(x, Wv, Wo, out);
  }
}

// Round 10
// 131.134 us; speedup vs baseline: 1.0223x; 1.0110x over previous
//
#include <hip/hip_runtime.h>

// LlamaAttention — Round 17: burst-issue x-stage (full MLP) + r16 K-loop.
//
// out = x @ (Wo @ Wv)^T  (softmax == I, established r0-r16).
// r16 post-mortem: asm B-pipeline held (VGPR 112 + AGPR acc) yet time
// unchanged -> B-latency exonerated. Counter arithmetic: avg HBM 1.9 TB/s;
// the x-stage's load->cvt->ds_write chain caps in-flight loads at ~2-4/wave
// -> stage is ~22us of the 42 (latency-bound), not 8. r17: issue ALL 24
// x global_load_dwordx4 asm-pinned FIRST (196 KB in flight/CU -> HBM-rate
// streaming), then the 18 B-prologue loads, vmcnt(18) retires exactly the
// x loads (B stays in flight), cvt+write from held regs, lgkm+s_barrier,
// then r16's counted-vmcnt K-loop verbatim. Peak live regs: stage 184,
// K-loop 200 (< 256 @ 2 waves/SIMD; acc declared after barrier).

typedef unsigned short u16;
typedef __attribute__((ext_vector_type(8))) short short8;      // 16 B
typedef __attribute__((ext_vector_type(8))) _Float16 f16x8;    // 4 VGPR MFMA frag
typedef __attribute__((ext_vector_type(4))) float float4v;

__device__ inline u16 f16b(float f) {
  union { _Float16 h; u16 u; } v; v.h = (_Float16)f; return v.u;  // v_cvt_f16_f32 RNE
}

__device__ inline u16 f32_to_bf16(float f) {        // fallback path only
  union { float f; unsigned int u; } v; v.f = f;
  unsigned int r = v.u + 0x7FFF + ((v.u >> 16) & 1);
  return (u16)(r >> 16);
}

// ---------------- prep: W = Wo @ Wv, fp32 accum, f16 tiled ----------------
// wt layout: element (o, h) at wt[(h>>5)*24576 + o*32 + ((h>>3)&3)*8 + (h&7)]
// (wave frag load = 1 KB contiguous). Bit-identical W vs r10-r16.
__global__ __launch_bounds__(256)
void prep_w(const float* __restrict__ Wv, const float* __restrict__ Wo,
            u16* __restrict__ wt) {
  __shared__ __align__(16) float wo[4][256];            // 4 KB
  const int og = blockIdx.x / 3, hc = blockIdx.x % 3;   // 192 o-grp x 3 h-chunk
  const int o0 = og * 4;
  ((float4v*)&wo[0][0])[threadIdx.x] =
      ((const float4v*)(Wo + (size_t)o0 * 256))[threadIdx.x];
  __syncthreads();
  const int h = hc * 256 + threadIdx.x;
  float acc[4] = {0.f, 0.f, 0.f, 0.f};
  float wvA[8], wvB[8];
#pragma unroll
  for (int u = 0; u < 8; ++u) wvA[u] = Wv[(size_t)u * 768 + h];

#define PFMA(wv_, kk_)                                                       \
  _Pragma("unroll")                                                          \
  for (int j = 0; j < 4; ++j) {                                              \
    float4v c0 = *(const float4v*)(&wo[j][kk_]);                             \
    float4v c1 = *(const float4v*)(&wo[j][(kk_) + 4]);                       \
    acc[j] = fmaf(c0[0], wv_[0], acc[j]);                                    \
    acc[j] = fmaf(c0[1], wv_[1], acc[j]);                                    \
    acc[j] = fmaf(c0[2], wv_[2], acc[j]);                                    \
    acc[j] = fmaf(c0[3], wv_[3], acc[j]);                                    \
    acc[j] = fmaf(c1[0], wv_[4], acc[j]);                                    \
    acc[j] = fmaf(c1[1], wv_[5], acc[j]);                                    \
    acc[j] = fmaf(c1[2], wv_[6], acc[j]);                                    \
    acc[j] = fmaf(c1[3], wv_[7], acc[j]);                                    \
  }

  for (int k = 0; k < 240; k += 16) {
#pragma unroll
    for (int u = 0; u < 8; ++u) wvB[u] = Wv[(size_t)(k + 8 + u) * 768 + h];
    PFMA(wvA, k)
#pragma unroll
    for (int u = 0; u < 8; ++u) wvA[u] = Wv[(size_t)(k + 16 + u) * 768 + h];
    PFMA(wvB, k + 8)
  }
#pragma unroll
  for (int u = 0; u < 8; ++u) wvB[u] = Wv[(size_t)(248 + u) * 768 + h];
  PFMA(wvA, 240)
  PFMA(wvB, 248)
#undef PFMA

  const int kt = h >> 5, qq = (h >> 3) & 3, e = h & 7;
#pragma unroll
  for (int j = 0; j < 4; ++j)
    wt[(size_t)kt * 24576 + (o0 + j) * 32 + qq * 8 + e] = f16b(acc[j]);
}

// ---------------- main: out[16384,768] = x @ W^T, asm-pinned pipeline -----
// Block: 512 thr / 8 waves; 64 rows x 768 cols; wave w owns cols w*96..+95
// (disjoint -> W read once per block). LDS: x stripe f16 [64][96 chunks],
// chunk stored at c^(row&7) (A-frag reads 2-way max = free).
__global__ __launch_bounds__(512, 2)
void gemm_xw(const float* __restrict__ x, const u16* __restrict__ wt,
             float* __restrict__ out) {
  __shared__ __align__(16) u16 S[64 * 768];       // 96 KB -> 1 block/CU

  const int tid = threadIdx.x;
  const int w = tid >> 6, l = tid & 63;
  const int q = l >> 4, mr = l & 15;
  const int row0 = blockIdx.x * 64;

  // B-frag lane base: wt + col*32 + q*8, col = w*96 + jn*16 + mr
  const u16* wl = wt + (w * 96 + mr) * 32 + q * 8;
  const int akey = mr & 7;

  f16x8 a0[4], a1[4], a2[4], b0[6], b1[6], b2[6];

// One 16B global load, asm-pinned (compiler cannot sink/serialize it).
#define GLD_OFF(dst_, base_, OFFSTR)                                         \
  asm volatile("global_load_dwordx4 %0, %1, off offset:" OFFSTR              \
               : "=v"(dst_) : "v"(base_) : "memory");

// jn stride = 512 u16 = 1024 B; offsets must stay < 4096 -> two bases.
#define LDB_ASM(bv_, kt_)                                                    \
  { const u16* gbase  = wl + (size_t)(kt_) * 24576;                          \
    const u16* gbase2 = gbase + 2048;                                        \
    GLD_OFF(bv_[0], gbase,  "0")                                             \
    GLD_OFF(bv_[1], gbase,  "1024")                                          \
    GLD_OFF(bv_[2], gbase,  "2048")                                          \
    GLD_OFF(bv_[3], gbase,  "3072")                                          \
    GLD_OFF(bv_[4], gbase2, "0")                                             \
    GLD_OFF(bv_[5], gbase2, "1024") }

#define LDA(av_, kt_)                                                        \
  _Pragma("unroll")                                                          \
  for (int im = 0; im < 4; ++im)                                             \
    av_[im] = *(const f16x8*)(                                               \
        &S[(im * 16 + mr) * 768 + ((((kt_) * 4 + q) ^ akey) << 3)]);

// Counted wait + scheduling fence (rule #18: MFMA/VALU hoists past asm
// waitcnt without sched_barrier).
#define WAITB(NSTR)                                                          \
  asm volatile("s_waitcnt vmcnt(" NSTR ")" ::: "memory");                    \
  __builtin_amdgcn_sched_barrier(0);

#define MM(av_, bv_)                                                         \
  { __builtin_amdgcn_s_setprio(1);                                           \
    _Pragma("unroll")                                                        \
    for (int im = 0; im < 4; ++im)                                           \
      _Pragma("unroll")                                                      \
      for (int jn = 0; jn < 6; ++jn)                                         \
        acc[im][jn] = __builtin_amdgcn_mfma_f32_16x16x32_f16(                \
            av_[im], bv_[jn], acc[im][jn], 0, 0, 0);                         \
    __builtin_amdgcn_s_setprio(0); }

  // ---- phase A: burst-issue ALL 24 x loads (oldest in vm FIFO) ----
  // Thread's chunks: c(j) = q + 4*(2j + half), j=0..11; address stride
  // 256 B -> one base + literal offsets (j*256 and j*256+16).
  const int sr = ((w & 3) << 4) + mr;             // row 0..63
  const int half = w >> 2;                        // even/odd chunk quads
  const float* gr = x + (size_t)(row0 + sr) * 768 + ((q + 4 * half) << 3);
  u16* lr = S + sr * 768;
  const int key = sr & 7;

  float4v xv0a, xv0b, xv1a, xv1b, xv2a, xv2b, xv3a, xv3b;
  float4v xv4a, xv4b, xv5a, xv5b, xv6a, xv6b, xv7a, xv7b;
  float4v xv8a, xv8b, xv9a, xv9b, xv10a, xv10b, xv11a, xv11b;

  GLD_OFF(xv0a,  gr, "0")    GLD_OFF(xv0b,  gr, "16")
  GLD_OFF(xv1a,  gr, "256")  GLD_OFF(xv1b,  gr, "272")
  GLD_OFF(xv2a,  gr, "512")  GLD_OFF(xv2b,  gr, "528")
  GLD_OFF(xv3a,  gr, "768")  GLD_OFF(xv3b,  gr, "784")
  GLD_OFF(xv4a,  gr, "1024") GLD_OFF(xv4b,  gr, "1040")
  GLD_OFF(xv5a,  gr, "1280") GLD_OFF(xv5b,  gr, "1296")
  GLD_OFF(xv6a,  gr, "1536") GLD_OFF(xv6b,  gr, "1552")
  GLD_OFF(xv7a,  gr, "1792") GLD_OFF(xv7b,  gr, "1808")
  GLD_OFF(xv8a,  gr, "2048") GLD_OFF(xv8b,  gr, "2064")
  GLD_OFF(xv9a,  gr, "2304") GLD_OFF(xv9b,  gr, "2320")
  GLD_OFF(xv10a, gr, "2560") GLD_OFF(xv10b, gr, "2576")
  GLD_OFF(xv11a, gr, "2816") GLD_OFF(xv11b, gr, "2832")

  // ---- B prologue: 18 loads, younger than all x loads in the FIFO ----
  LDB_ASM(b0, 0)
  LDB_ASM(b1, 1)
  LDB_ASM(b2, 2)

  // Retire exactly the 24 x loads; 18 B loads stay in flight.
  WAITB("18")

  // ---- cvt + swizzled LDS writes from held registers ----
#define CVTW(J, va_, vb_)                                                    \
  { const int c = q + 4 * (2 * (J) + half);                                  \
    union { u16 h[8]; short8 s; } p;                                         \
    _Pragma("unroll")                                                        \
    for (int e = 0; e < 4; ++e) { p.h[e] = f16b(va_[e]); p.h[e + 4] = f16b(vb_[e]); } \
    *(short8*)(lr + ((c ^ key) << 3)) = p.s; }

  CVTW(0, xv0a, xv0b)   CVTW(1, xv1a, xv1b)   CVTW(2, xv2a, xv2b)
  CVTW(3, xv3a, xv3b)   CVTW(4, xv4a, xv4b)   CVTW(5, xv5a, xv5b)
  CVTW(6, xv6a, xv6b)   CVTW(7, xv7a, xv7b)   CVTW(8, xv8a, xv8b)
  CVTW(9, xv9a, xv9b)   CVTW(10, xv10a, xv10b) CVTW(11, xv11a, xv11b)
#undef CVTW

  // Raw barrier: drain only LDS writes; B loads STAY in flight.
  asm volatile("s_waitcnt lgkmcnt(0)" ::: "memory");
  __builtin_amdgcn_s_barrier();

  float4v acc[4][6];
#pragma unroll
  for (int i = 0; i < 4; ++i)
#pragma unroll
    for (int j = 0; j < 6; ++j) acc[i][j] = (float4v){0.f, 0.f, 0.f, 0.f};

  LDA(a0, 0)
  LDA(a1, 1)
  LDA(a2, 2)

  // ---- steady: uniform body, 2 B-tiles always in flight ----
  // Invariant at each WAITB(12): 18 B loads outstanding; retires oldest 6.
  for (int t = 0; t < 21; t += 3) {
    WAITB("12") MM(a0, b0) LDB_ASM(b0, t + 3) LDA(a0, t + 3)
    WAITB("12") MM(a1, b1) LDB_ASM(b1, t + 4) LDA(a1, t + 4)
    WAITB("12") MM(a2, b2) LDB_ASM(b2, t + 5) LDA(a2, t + 5)
  }
  // tail: tiles 21, 22, 23 already issued (and a-sets loaded) at t=18
  WAITB("12") MM(a0, b0)
  WAITB("6")  MM(a1, b1)
  WAITB("0")  MM(a2, b2)

#undef GLD_OFF
#undef LDB_ASM
#undef LDA
#undef WAITB
#undef MM

  // ---- epilogue: C/D col=lane&15, row=q*4+reg (m89-verified) ----
#pragma unroll
  for (int im = 0; im < 4; ++im)
#pragma unroll
    for (int jn = 0; jn < 6; ++jn) {
      const int r0 = row0 + im * 16 + q * 4;
      const int c  = w * 96 + jn * 16 + mr;
#pragma unroll
      for (int r = 0; r < 4; ++r)
        out[(size_t)(r0 + r) * 768 + c] = acc[im][jn][r];
    }
}

// ---------------- fallback (no workspace): verified r7 kernel ----------------
__global__ __launch_bounds__(512, 1)
void fused_fallback(const float* __restrict__ x,
                    const float* __restrict__ Wv, const float* __restrict__ Wo,
                    float* __restrict__ out) {
  __shared__ __align__(16) u16 As[64 * 32];
  __shared__ __align__(16) u16 Bs[256 * 32];
  __shared__ __align__(16) u16 Vs[64 * 264];

  const int tid = threadIdx.x;
  const int w  = tid >> 6, l = tid & 63;
  const int q  = l >> 4, mr = l & 15;
  const int wm = w & 1, wn = w >> 1;
  const int row0 = blockIdx.x * 64;
  const int xr = tid >> 3, xg = (tid & 7) * 4;
  const int wr = tid >> 1, wh = (tid & 1) * 16;

  float4v acc[2][4];
#pragma unroll
  for (int i = 0; i < 2; ++i)
#pragma unroll
    for (int j = 0; j < 4; ++j) acc[i][j] = (float4v){0.f, 0.f, 0.f, 0.f};

  for (int kt = 0; kt < 24; ++kt) {
    const int k0 = kt * 32;
    {
      float4v v = *(const float4v*)(x + (size_t)(row0 + xr) * 768 + k0 + xg);
      union { u16 h[4]; uint2 u; } p;
      p.h[0] = f32_to_bf16(v[0]); p.h[1] = f32_to_bf16(v[1]);
      p.h[2] = f32_to_bf16(v[2]); p.h[3] = f32_to_bf16(v[3]);
      *(uint2*)(As + xr * 32 + xg) = p.u;
    }
    {
      const float* g = Wv + (size_t)wr * 768 + k0 + wh;
      union { u16 h[16]; short8 s[2]; } p;
#pragma unroll
      for (int u = 0; u < 4; ++u) {
        float4v v = *(const float4v*)(g + u * 4);
        p.h[u * 4 + 0] = f32_to_bf16(v[0]); p.h[u * 4 + 1] = f32_to_bf16(v[1]);
        p.h[u * 4 + 2] = f32_to_bf16(v[2]); p.h[u * 4 + 3] = f32_to_bf16(v[3]);
      }
      *(short8*)(Bs + wr * 32 + wh) = p.s[0];
      *(short8*)(Bs + wr * 32 + wh + 8) = p.s[1];
    }
    __syncthreads();

    short8 a[2], b[4];
#pragma unroll
    for (int i = 0; i < 2; ++i)
      a[i] = *(const short8*)(As + (wm * 32 + i * 16 + mr) * 32 + q * 8);
#pragma unroll
    for (int j = 0; j < 4; ++j)
      b[j] = *(const short8*)(Bs + (wn * 64 + j * 16 + mr) * 32 + q * 8);
#pragma unroll
    for (int i = 0; i < 2; ++i)
#pragma unroll
      for (int j = 0; j < 4; ++j)
        acc[i][j] = __builtin_amdgcn_mfma_f32_16x16x32_bf16(a[i], b[j], acc[i][j], 0, 0, 0);
    __syncthreads();
  }

#pragma unroll
  for (int i = 0; i < 2; ++i)
#pragma unroll
    for (int j = 0; j < 4; ++j) {
      int row = wm * 32 + i * 16 + q * 4;
      int col = wn * 64 + j * 16 + mr;
#pragma unroll
      for (int r = 0; r < 4; ++r)
        Vs[(row + r) * 264 + col] = f32_to_bf16(acc[i][j][r]);
    }
  __syncthreads();

  for (int c = 0; c < 3; ++c) {
    float4v acc2[2][4];
#pragma unroll
    for (int i = 0; i < 2; ++i)
#pragma unroll
      for (int j = 0; j < 4; ++j) acc2[i][j] = (float4v){0.f, 0.f, 0.f, 0.f};

    for (int kt = 0; kt < 8; ++kt) {
      const int k0 = kt * 32;
      {
        const float* g = Wo + (size_t)(c * 256 + wr) * 256 + k0 + wh;
        union { u16 h[16]; short8 s[2]; } p;
#pragma unroll
        for (int u = 0; u < 4; ++u) {
          float4v v = *(const float4v*)(g + u * 4);
          p.h[u * 4 + 0] = f32_to_bf16(v[0]); p.h[u * 4 + 1] = f32_to_bf16(v[1]);
          p.h[u * 4 + 2] = f32_to_bf16(v[2]); p.h[u * 4 + 3] = f32_to_bf16(v[3]);
        }
        *(short8*)(Bs + wr * 32 + wh) = p.s[0];
        *(short8*)(Bs + wr * 32 + wh + 8) = p.s[1];
      }
      __syncthreads();

      short8 a[2], b[4];
#pragma unroll
      for (int i = 0; i < 2; ++i)
        a[i] = *(const short8*)(Vs + (wm * 32 + i * 16 + mr) * 264 + k0 + q * 8);
#pragma unroll
      for (int j = 0; j < 4; ++j)
        b[j] = *(const short8*)(Bs + (wn * 64 + j * 16 + mr) * 32 + q * 8);
#pragma unroll
      for (int i = 0; i < 2; ++i)
#pragma unroll
        for (int j = 0; j < 4; ++j)
          acc2[i][j] = __builtin_amdgcn_mfma_f32_16x16x32_bf16(a[i], b[j], acc2[i][j], 0, 0, 0);
      __syncthreads();
    }

#pragma unroll
    for (int i = 0; i < 2; ++i)
#pragma unroll
      for (int j = 0; j < 4; ++j) {
        int row = row0 + wm * 32 + i * 16 + q * 4;
        int col = c * 256 + wn * 64 + j * 16 + mr;
#pragma unroll
        for (int r = 0; r < 4; ++r)
          out[(size_t)(row + r) * 768 + col] = acc2[i][j][r];
      }
  }
}

extern "C" void kernel_launch(void* const* d_in, const int* in_sizes, int n_in,
                              void* d_out, int out_size, void* d_ws, size_t ws_size,
                              hipStream_t stream) {
  (void)in_sizes; (void)n_in; (void)out_size;
  const float* x  = (const float*)d_in[0];  // [16384, 768]
  const float* Wv = (const float*)d_in[3];  // [256, 768]
  const float* Wo = (const float*)d_in[4];  // [768, 256]
  float* out = (float*)d_out;

  if (ws_size >= (size_t)768 * 768 * 2) {   // 1.18 MB f16 combined weight
    u16* wt = (u16*)d_ws;
    prep_w<<<dim3(576), dim3(256), 0, stream>>>(Wv, Wo, wt);
    gemm_xw<<<dim3(256), dim3(512), 0, stream>>>(x, wt, out);
  } else {
    fused_fallback<<<dim3(256), dim3(512), 0, stream>>>(x, Wv, Wo, out);
  }
}